// Round 18
// baseline (3656.787 us; speedup 1.0000x reference)
//
#include <hip/hip_runtime.h>

typedef unsigned short u16;
typedef __attribute__((ext_vector_type(8))) short short8;
typedef __attribute__((ext_vector_type(4))) float f32x4;

#define DEVFUN __device__ __forceinline__

namespace {

constexpr int kB = 128;
constexpr int kN = 512;   // N == M
constexpr int kD = 256;
constexpr int kF = 512;
constexpr int kL = 5;
constexpr float kEPS = 1e-5f;
constexpr long BND = (long)kB * kN * kD;  // 16,777,216

DEVFUN float bf2f(u16 u) {
  unsigned v = ((unsigned)u) << 16;
  float f;
  __builtin_memcpy(&f, &v, 4);
  return f;
}
DEVFUN u16 f2bf(float f) {  // round-to-nearest-even
  unsigned x;
  __builtin_memcpy(&x, &f, 4);
  x = (x + 0x7FFFu + ((x >> 16) & 1u)) >> 16;
  return (u16)x;
}
DEVFUN u16 f2h(float f) {
  _Float16 h = (_Float16)f;
  u16 u;
  __builtin_memcpy(&u, &h, 2);
  return u;
}
DEVFUN float h2f(u16 u) {
  _Float16 h;
  __builtin_memcpy(&h, &u, 2);
  return (float)h;
}
DEVFUN float fsig(float x) { return 1.f / (1.f + __expf(-x)); }

union Pk8 { u16 p[8]; uint4 v; };
union Pk4 { u16 p[4]; uint2 v; };

// async global->LDS, 16B per lane; LDS dest wave-uniform base + lane*16
DEVFUN void gload16(const u16* g, u16* l) {
  __builtin_amdgcn_global_load_lds(
      (const __attribute__((address_space(1))) void*)g,
      (__attribute__((address_space(3))) void*)l, 16, 0, 0);
}

DEVFUN void waitv8() { asm volatile("s_waitcnt vmcnt(8)" ::: "memory"); }
DEVFUN void waitv0() { asm volatile("s_waitcnt vmcnt(0)" ::: "memory"); }

// ---------------- transpose fp32 -> {bf16, exp-bf16, fp16} ----------------
template <int MODE>
__global__ __launch_bounds__(256) void tcvt(const float* __restrict__ src,
                                            u16* __restrict__ dst, int R,
                                            int C, const float* __restrict__ al,
                                            int pi, const float* __restrict__ ls) {
  __shared__ u16 T[64 * 64];
  const int t = threadIdx.x;
  const long z = blockIdx.z;
  const int cBase = blockIdx.x * 64, rBase = blockIdx.y * 64;
  float s = 0.f;
  if constexpr (MODE == 1) s = -al[pi] * ls[0];
#pragma unroll
  for (int i = 0; i < 4; ++i) {
    int u = i * 256 + t;
    int n = u >> 4, m4 = u & 15;
    float4 v = *(const float4*)(src + (z * R + rBase + n) * C + cBase + m4 * 4);
    Pk4 pk;
    if constexpr (MODE == 1) {
      pk.p[0] = f2bf(__expf(s * v.x)); pk.p[1] = f2bf(__expf(s * v.y));
      pk.p[2] = f2bf(__expf(s * v.z)); pk.p[3] = f2bf(__expf(s * v.w));
    } else if constexpr (MODE == 2) {
      pk.p[0] = f2h(v.x); pk.p[1] = f2h(v.y);
      pk.p[2] = f2h(v.z); pk.p[3] = f2h(v.w);
    } else {
      pk.p[0] = f2bf(v.x); pk.p[1] = f2bf(v.y);
      pk.p[2] = f2bf(v.z); pk.p[3] = f2bf(v.w);
    }
    int ch = (m4 >> 1) ^ ((n >> 3) & 7), hf = m4 & 1;
    *(uint2*)&T[n * 64 + ch * 8 + hf * 4] = pk.v;
  }
  __syncthreads();
#pragma unroll
  for (int j = 0; j < 2; ++j) {
    int u = j * 256 + t;
    int om = u >> 3, nc = u & 7;
    Pk8 pk;
#pragma unroll
    for (int i = 0; i < 8; ++i) {
      int n = nc * 8 + i;
      int ch = (om >> 3) ^ ((n >> 3) & 7);
      pk.p[i] = T[n * 64 + ch * 8 + (om & 7)];
    }
    *(uint4*)(dst + (z * C + cBase + om) * R + rBase + nc * 8) = pk.v;
  }
}

// ------------- elementwise exp from f32: E = bf16(exp(s*x)) --------------
__global__ __launch_bounds__(256) void eexp(const float* __restrict__ src,
                                            u16* __restrict__ dst, long n8,
                                            const float* __restrict__ al,
                                            int pi, const float* __restrict__ ls) {
  const float s = -al[pi] * ls[0];
  for (long i = blockIdx.x * 256 + threadIdx.x; i < n8;
       i += (long)gridDim.x * 256) {
    const float* p = src + i * 8;
    float4 v0 = *(const float4*)p, v1 = *(const float4*)(p + 4);
    Pk8 pk;
    pk.p[0] = f2bf(__expf(s * v0.x)); pk.p[1] = f2bf(__expf(s * v0.y));
    pk.p[2] = f2bf(__expf(s * v0.z)); pk.p[3] = f2bf(__expf(s * v0.w));
    pk.p[4] = f2bf(__expf(s * v1.x)); pk.p[5] = f2bf(__expf(s * v1.y));
    pk.p[6] = f2bf(__expf(s * v1.z)); pk.p[7] = f2bf(__expf(s * v1.w));
    *(uint4*)(dst + i * 8) = pk.v;
  }
}

// ------------- elementwise exp from fp16: E = bf16(exp(s*x)) -------------
__global__ __launch_bounds__(256) void eexpH(const u16* __restrict__ src,
                                             u16* __restrict__ dst, long n8,
                                             const float* __restrict__ al,
                                             int pi, const float* __restrict__ ls) {
  const float s = -al[pi] * ls[0];
  for (long i = blockIdx.x * 256 + threadIdx.x; i < n8;
       i += (long)gridDim.x * 256) {
    Pk8 h;
    h.v = *(const uint4*)(src + i * 8);
    Pk8 pk;
#pragma unroll
    for (int q = 0; q < 8; ++q) pk.p[q] = f2bf(__expf(s * h2f(h.p[q])));
    *(uint4*)(dst + i * 8) = pk.v;
  }
}

// ------------- elementwise fp32 -> bf16 / fp16 ---------------------------
template <int MODE>  // 0 = bf16, 2 = fp16
__global__ __launch_bounds__(256) void cvtb(const float* __restrict__ src,
                                            u16* __restrict__ dst, long n8) {
  for (long i = blockIdx.x * 256 + threadIdx.x; i < n8;
       i += (long)gridDim.x * 256) {
    const float* p = src + i * 8;
    float4 v0 = *(const float4*)p, v1 = *(const float4*)(p + 4);
    Pk8 pk;
    if constexpr (MODE == 2) {
      pk.p[0] = f2h(v0.x); pk.p[1] = f2h(v0.y);
      pk.p[2] = f2h(v0.z); pk.p[3] = f2h(v0.w);
      pk.p[4] = f2h(v1.x); pk.p[5] = f2h(v1.y);
      pk.p[6] = f2h(v1.z); pk.p[7] = f2h(v1.w);
    } else {
      pk.p[0] = f2bf(v0.x); pk.p[1] = f2bf(v0.y);
      pk.p[2] = f2bf(v0.z); pk.p[3] = f2bf(v0.w);
      pk.p[4] = f2bf(v1.x); pk.p[5] = f2bf(v1.y);
      pk.p[6] = f2bf(v1.z); pk.p[7] = f2bf(v1.w);
    }
    *(uint4*)(dst + i * 8) = pk.v;
  }
}

// --------------- shared MFMA inner step (BK=64) ---------------------------
DEVFUN void mfma_step(const u16* As, const u16* Bs, int wr, int wc, int lr,
                      int lhi, f32x4 acc[4][4]) {
#pragma unroll
  for (int ks = 0; ks < 2; ++ks) {
    short8 af[4], bfr[4];
#pragma unroll
    for (int m = 0; m < 4; ++m) {
      int r = wr + m * 16 + lr;
      af[m] = *(const short8*)&As[r * 64 + (((ks << 2) + lhi) ^ (r & 7)) * 8];
    }
#pragma unroll
    for (int n = 0; n < 4; ++n) {
      int r = wc + n * 16 + lr;
      bfr[n] = *(const short8*)&Bs[r * 64 + (((ks << 2) + lhi) ^ (r & 7)) * 8];
    }
#pragma unroll
    for (int m = 0; m < 4; ++m)
#pragma unroll
      for (int n = 0; n < 4; ++n)
        acc[m][n] = __builtin_amdgcn_mfma_f32_16x16x32_bf16(af[m], bfr[n],
                                                            acc[m][n], 0, 0, 0);
  }
}

enum Epi { EP_SIG = 0, EP_RELUB, EP_BIASRES };

// C[65536 x NC] = A[65536 x K](bf16) @ WT[NC x K]^T(bf16); 128x128 tile,
// 2-buffer pipeline with counted vmcnt (R12-proven best for weight GEMMs).
// EP_BIASRES additionally emits partial (sum, sumsq) for the next inorm.
template <int EPI, int KK>
__global__ __launch_bounds__(256) void gemm_mf(
    const u16* __restrict__ Asrc, const u16* __restrict__ WT, int gx,
    void* __restrict__ outp, const void* __restrict__ aux,
    const u16* __restrict__ aux2b, float* __restrict__ statsF) {
  __shared__ u16 SM[4 * 8192];  // A0 B0 A1 B1, 16KB each
  const int t = threadIdx.x;
  const int lane = t & 63, wid = t >> 6;
  const int lr = lane & 15, lhi = lane >> 4;
  const int wr = (wid >> 1) * 64, wc = (wid & 1) * 64;
  const int cpx = gridDim.x >> 3;
  const int rb = (blockIdx.x & 7) * cpx + (blockIdx.x >> 3);
  const int bx = rb % gx;
  const long rowBase = (long)(rb / gx) * 128;
  const int colBase = bx * 128;
  const int r0 = wid * 32;
  const int rl = lane >> 3, sl = lane & 7;

  f32x4 acc[4][4];
#pragma unroll
  for (int m = 0; m < 4; ++m)
#pragma unroll
    for (int n = 0; n < 4; ++n) acc[m][n] = {0.f, 0.f, 0.f, 0.f};

  auto stage = [&](int tt, int pb) {
    const int kt = tt << 6;
    u16* As = SM + pb * 16384;
    u16* Bs = SM + pb * 16384 + 8192;
#pragma unroll
    for (int j = 0; j < 4; ++j) {
      int r = r0 + j * 8 + rl;
      int gch = sl ^ (r & 7);
      gload16(Asrc + (rowBase + r) * KK + kt + gch * 8, &As[(r0 + j * 8) * 64]);
      gload16(WT + (long)(colBase + r) * KK + kt + gch * 8,
              &Bs[(r0 + j * 8) * 64]);
    }
  };

  constexpr int NT = KK >> 6;  // 4 or 8
  stage(0, 0);
  stage(1, 1);
  waitv8();
  __builtin_amdgcn_s_barrier();
#pragma unroll
  for (int tt = 0; tt < NT - 1; ++tt) {
    mfma_step(SM + (tt & 1) * 16384, SM + (tt & 1) * 16384 + 8192, wr, wc, lr,
              lhi, acc);
    __builtin_amdgcn_s_barrier();
    if (tt + 2 < NT) {
      stage(tt + 2, tt & 1);
      waitv8();
    } else {
      waitv0();
    }
    __builtin_amdgcn_s_barrier();
  }
  mfma_step(SM + ((NT - 1) & 1) * 16384, SM + ((NT - 1) & 1) * 16384 + 8192,
            wr, wc, lr, lhi, acc);

  float psum[4] = {0.f, 0.f, 0.f, 0.f}, psq[4] = {0.f, 0.f, 0.f, 0.f};
#pragma unroll
  for (int m = 0; m < 4; ++m) {
#pragma unroll
    for (int n = 0; n < 4; ++n) {
#pragma unroll
      for (int rr = 0; rr < 4; ++rr) {
        float v = acc[m][n][rr];
        long grow = rowBase + wr + m * 16 + lhi * 4 + rr;
        int gcol = colBase + wc + n * 16 + lr;
        if constexpr (EPI == EP_SIG) {
          ((u16*)outp)[grow * 256 + gcol] = f2bf(fsig(v));
        } else if constexpr (EPI == EP_RELUB) {
          float bb = ((const float*)aux)[gcol];
          ((u16*)outp)[grow * 512 + gcol] = f2bf(fmaxf(v + bb, 0.f));
        } else {  // EP_BIASRES: bias + bf16 residual -> bf16 state + stats
          float bb = ((const float*)aux)[gcol];
          float y = v + bb + bf2f(aux2b[grow * 256 + gcol]);
          ((u16*)outp)[grow * 256 + gcol] = f2bf(y);
          psum[n] += y;
          psq[n] += y * y;
        }
      }
    }
  }

  if constexpr (EPI == EP_BIASRES) {
    __syncthreads();  // all LDS reads of the K-loop done; SM reuse safe
    float* stS = (float*)SM;        // [8][128]
    float* stQ = stS + 8 * 128;     // [8][128]
    const int ctr = (wid >> 1) * 4 + lhi;
#pragma unroll
    for (int n = 0; n < 4; ++n) {
      stS[ctr * 128 + wc + n * 16 + lr] = psum[n];
      stQ[ctr * 128 + wc + n * 16 + lr] = psq[n];
    }
    __syncthreads();
    if (t < 128) {
      float s = 0.f, q = 0.f;
#pragma unroll
      for (int i = 0; i < 8; ++i) {
        s += stS[i * 128 + t];
        q += stQ[i * 128 + t];
      }
      const long b = rowBase >> 9;
      const int rblk = (int)((rowBase >> 7) & 3);
      const long o = ((b * 4 + rblk) * 256 + colBase + t) * 2;
      statsF[o] = s;
      statsF[o + 1] = q;
    }
  }
}

// ---- fused K/V GEMM (128x128): ek = exp(x@Wk), ekv = ek*(x@Wv), written
// transposed+coalesced into CbufT ([b][d][m] ekv ; [b][256+d][m] ek).
union KvSm {
  struct { u16 A[128 * 64]; u16 Bk[128 * 64]; u16 Bv[128 * 64]; } s;  // 48KB
  u16 T[128 * 128];  // 32KB transpose staging
};

__global__ __launch_bounds__(256) void kv_mf(const u16* __restrict__ Asrc,
                                             const u16* __restrict__ WkT,
                                             const u16* __restrict__ WvT,
                                             u16* __restrict__ Cb) {
  __shared__ KvSm sm;
  const int t = threadIdx.x;
  const int lane = t & 63, wid = t >> 6;
  const int lr = lane & 15, lhi = lane >> 4;
  const int wr = (wid >> 1) * 64, wc = (wid & 1) * 64;
  const int cpx = gridDim.x >> 3;
  const int rb = (blockIdx.x & 7) * cpx + (blockIdx.x >> 3);
  const long rowBase = (long)(rb >> 1) * 128;
  const int colBase = (rb & 1) * 128;
  const long b = rowBase >> 9;
  const int mInB = (int)(rowBase & 511);
  const int r0 = wid * 32;
  const int rl = lane >> 3, sl = lane & 7;

  f32x4 ka[4][4], va[4][4];
#pragma unroll
  for (int m = 0; m < 4; ++m)
#pragma unroll
    for (int n = 0; n < 4; ++n) {
      ka[m][n] = {0.f, 0.f, 0.f, 0.f};
      va[m][n] = {0.f, 0.f, 0.f, 0.f};
    }

  for (int kt = 0; kt < 256; kt += 64) {
#pragma unroll
    for (int j = 0; j < 4; ++j) {
      int r = r0 + j * 8 + rl;
      int gch = sl ^ (r & 7);
      gload16(Asrc + (rowBase + r) * 256 + kt + gch * 8,
              &sm.s.A[(r0 + j * 8) * 64]);
      gload16(WkT + (long)(colBase + r) * 256 + kt + gch * 8,
              &sm.s.Bk[(r0 + j * 8) * 64]);
      gload16(WvT + (long)(colBase + r) * 256 + kt + gch * 8,
              &sm.s.Bv[(r0 + j * 8) * 64]);
    }
    __syncthreads();
    mfma_step(sm.s.A, sm.s.Bk, wr, wc, lr, lhi, ka);
    mfma_step(sm.s.A, sm.s.Bv, wr, wc, lr, lhi, va);
    __syncthreads();
  }

#pragma unroll
  for (int pass = 0; pass < 2; ++pass) {
#pragma unroll
    for (int m = 0; m < 4; ++m) {
#pragma unroll
      for (int n = 0; n < 4; ++n) {
        int m0 = wr + m * 16 + lhi * 4;
        int d = wc + n * 16 + lr;
        Pk4 pk;
#pragma unroll
        for (int rr = 0; rr < 4; ++rr) {
          float ek = __expf(ka[m][n][rr]);
          pk.p[rr] = f2bf(pass ? ek * va[m][n][rr] : ek);
        }
        int slot = (m0 >> 3) ^ (d & 7);
        *(uint2*)&sm.T[d * 128 + slot * 8 + (m0 & 7)] = pk.v;
      }
    }
    __syncthreads();
    const long rbase = b * 512 + (pass ? 0 : 256) + colBase;
#pragma unroll
    for (int j = 0; j < 8; ++j) {
      int idx = j * 256 + t;
      int d = idx >> 4, c = idx & 15;
      uint4 v = *(const uint4*)&sm.T[d * 128 + ((c ^ (d & 7)) * 8)];
      *(uint4*)(Cb + (rbase + d) * 512 + mInB + c * 8) = v;
    }
    __syncthreads();
  }
}

// ---- fused AFT (8 waves, 128n x 128d per block): halves E logical reads.
// LDS: A = E[128][64] (16KB) | B = [ekv 128 | ek 128][64] (32KB).
// Wave (wn = wid>>2, wq = wid&3): 64 n-rows x 64-col group of [num|den].
__global__ __launch_bounds__(512) void aft_mf(
    const u16* __restrict__ Ebuf, const u16* __restrict__ CbufT,
    const u16* __restrict__ qb, const u16* __restrict__ xrB,
    u16* __restrict__ dst, float* __restrict__ statsF) {
  __shared__ u16 SM[24576];  // 48KB
  u16* const As = SM;         // 128 x 64
  u16* const Bs = SM + 8192;  // 256 x 64
  const int t = threadIdx.x;
  const int lane = t & 63, wid = t >> 6;
  const int lr = lane & 15, lhi = lane >> 4;
  const int wn = wid >> 2, wq = wid & 3;
  // XCD-chunked swizzle over 1024 blocks
  const int rb = (blockIdx.x & 7) * 128 + (blockIdx.x >> 3);
  const long b = rb >> 3;
  const int nBase = ((rb >> 1) & 3) * 128;
  const int dBase = (rb & 1) * 128;
  const int rl = lane >> 3, sl = lane & 7;

  f32x4 acc[4][4];
#pragma unroll
  for (int m = 0; m < 4; ++m)
#pragma unroll
    for (int n = 0; n < 4; ++n) acc[m][n] = {0.f, 0.f, 0.f, 0.f};

  for (int kt = 0; kt < 512; kt += 64) {
#pragma unroll
    for (int j = 0; j < 6; ++j) {  // 48 chunks of 8 rows; wave gets 6
      int c = wid * 6 + j;
      if (c < 16) {  // A chunk (wave-uniform branch)
        int r = c * 8 + rl;
        int gch = sl ^ (r & 7);
        gload16(Ebuf + (b * 512 + nBase + r) * 512 + kt + gch * 8,
                &As[c * 512]);
      } else {  // B chunk
        int rbl = (c - 16) * 8 + rl;  // 0..255
        int gch = sl ^ (rbl & 7);
        int gslot = (rbl < 128) ? (dBase + rbl) : (256 + dBase + (rbl - 128));
        gload16(CbufT + (b * 512 + gslot) * 512 + kt + gch * 8,
                &Bs[(c - 16) * 512]);
      }
    }
    __syncthreads();
    mfma_step(As, Bs, wn * 64, wq * 64, lr, lhi, acc);
    __syncthreads();
  }

  const bool isNum = (wq < 2);
  float* const den = (float*)SM;  // 64 x 132 f32 = 33.8KB (post-loop reuse)
  float psum[4] = {0.f, 0.f, 0.f, 0.f}, psq[4] = {0.f, 0.f, 0.f, 0.f};
#pragma unroll
  for (int ph = 0; ph < 2; ++ph) {
    __syncthreads();
    if (wn == ph && !isNum) {  // den waves write 64x128 slab
#pragma unroll
      for (int m = 0; m < 4; ++m)
#pragma unroll
        for (int n = 0; n < 4; ++n)
#pragma unroll
          for (int rr = 0; rr < 4; ++rr) {
            int rowl = m * 16 + lhi * 4 + rr;
            int dl = (wq - 2) * 64 + n * 16 + lr;
            den[rowl * 132 + dl] = acc[m][n][rr];
          }
    }
    __syncthreads();
    if (wn == ph && isNum) {  // num waves combine + epilogue
#pragma unroll
      for (int m = 0; m < 4; ++m)
#pragma unroll
        for (int n = 0; n < 4; ++n)
#pragma unroll
          for (int rr = 0; rr < 4; ++rr) {
            int rowl = m * 16 + lhi * 4 + rr;
            int dl = wq * 64 + n * 16 + lr;
            float dv = den[rowl * 132 + dl];
            float w = acc[m][n][rr] / dv;
            if (!(w == w)) w = 0.f;
            else if (w > 3.402823466e38f) w = 3.402823466e38f;
            else if (w < -3.402823466e38f) w = -3.402823466e38f;
            long grow = b * 512 + nBase + wn * 64 + rowl;
            int gcol = dBase + dl;
            float sq = bf2f(qb[grow * 256 + gcol]);
            float y = bf2f(xrB[grow * 256 + gcol]) + sq * w;
            dst[grow * 256 + gcol] = f2bf(y);
            psum[n] += y;
            psq[n] += y * y;
          }
    }
  }
  __syncthreads();  // den reads complete; stats region reuse safe
  float* const stS = (float*)SM;       // [8][128]
  float* const stQ = stS + 8 * 128;    // [8][128]
  if (isNum) {
    const int ctr = wn * 4 + lhi;
#pragma unroll
    for (int n = 0; n < 4; ++n) {
      stS[ctr * 128 + wq * 64 + n * 16 + lr] = psum[n];
      stQ[ctr * 128 + wq * 64 + n * 16 + lr] = psq[n];
    }
  }
  __syncthreads();
  if (t < 128) {
    float s = 0.f, q = 0.f;
#pragma unroll
    for (int i = 0; i < 8; ++i) {
      s += stS[i * 128 + t];
      q += stQ[i * 128 + t];
    }
    const long o = ((b * 4 + (nBase >> 7)) * 256 + dBase + t) * 2;
    statsF[o] = s;
    statsF[o + 1] = q;
  }
}

// ----- instance norm apply (single pass); stats from producer kernels -----
// Scalar access pattern (measured faster than vectorized); rows split
// across blockIdx.z for extra TLP.
template <bool LASTF32>
__global__ __launch_bounds__(256) void inormS(const u16* __restrict__ Xin,
                                              const float* __restrict__ stats,
                                              const float* __restrict__ g,
                                              const float* __restrict__ be,
                                              u16* __restrict__ Xb,
                                              float* __restrict__ Xf) {
  const int b = blockIdx.x;
  const int ch0 = blockIdx.y * 64;
  const int nlo = blockIdx.z * 256;
  const int t = threadIdx.x;
  const int lc = t & 63;
  const int ch = ch0 + lc;
  const int nr = t >> 6;
  const long base = (long)b * kN * kD + ch;

  __shared__ float s1[4][64], s2[4][64];
  __shared__ float mu[64], rs[64], gg[64], bb[64];
  {
    const long o = (((long)b * 4 + nr) * 256 + ch) * 2;
    s1[nr][lc] = stats[o];
    s2[nr][lc] = stats[o + 1];
  }
  __syncthreads();
  if (t < 64) {
    float ssum = s1[0][t] + s1[1][t] + s1[2][t] + s1[3][t];
    float ssq = s2[0][t] + s2[1][t] + s2[2][t] + s2[3][t];
    float m = ssum * (1.f / kN);
    float v = ssq * (1.f / kN) - m * m;
    mu[t] = m;
    rs[t] = rsqrtf(v + kEPS);
    gg[t] = g[ch0 + t];
    bb[t] = be[ch0 + t];
  }
  __syncthreads();
  const float m = mu[lc], rr = rs[lc], G = gg[lc], Bt = bb[lc];
  for (int n = nlo + nr; n < nlo + 256; n += 4) {
    long idx = base + (long)n * kD;
    float y = (bf2f(Xin[idx]) - m) * rr * G + Bt;
    Xb[idx] = f2bf(y);
    if constexpr (LASTF32) Xf[idx] = y;
  }
}

}  // namespace

extern "C" void kernel_launch(void* const* d_in, const int* in_sizes, int n_in,
                              void* d_out, int out_size, void* d_ws,
                              size_t ws_size, hipStream_t stream) {
  (void)in_sizes; (void)n_in; (void)out_size;

  const float* in_row = (const float*)d_in[0];
  const float* in_col = (const float*)d_in[1];
  const float* cost = (const float*)d_in[2];
  const float* lsc = (const float*)d_in[3];
  const float* Wq = (const float*)d_in[4];
  const float* Wk = (const float*)d_in[5];
  const float* Wv = (const float*)d_in[6];
  const float* g1 = (const float*)d_in[7];
  const float* be1 = (const float*)d_in[8];
  const float* W1 = (const float*)d_in[9];
  const float* b1 = (const float*)d_in[10];
  const float* W2 = (const float*)d_in[11];
  const float* b2 = (const float*)d_in[12];
  const float* g2 = (const float*)d_in[13];
  const float* be2 = (const float*)d_in[14];
  const float* alpha = (const float*)d_in[15];

  float* outRow = (float*)d_out;
  float* outCol = outRow + BND;

  u16* qb = (u16*)d_ws;                 // BND (sigmoid q; alias h1b)
  u16* h1b = qb;
  u16* CbufT = qb + BND;                // 2*BND
  u16* ffmid = CbufT;                   // alias (dead after AFT)
  u16* Ebuf = CbufT + 2 * BND;          // 2*BND
  u16* bSt = Ebuf + 2 * BND;            // 4*BND states [parity][side]
  u16* h0b = bSt + 4 * BND;             // BND (aft out; alias h2b)
  u16* h2b = h0b;
  u16* WqT = h0b + BND;
  u16* WkT = WqT + 10L * 256 * 256;
  u16* WvT = WkT + 10L * 256 * 256;
  u16* W1T = WvT + 10L * 256 * 256;     // [pi][f=512][d=256]
  u16* W2T = W1T + 10L * 512 * 256;     // [pi][d=256][f=512]
  float* statsF = (float*)(W2T + 10L * 256 * 512);  // [128][4][256][2] f32
  u16* costTH = (u16*)(statsF + 128L * 4 * 256 * 2);  // 2*BND fp16: cost^T
  u16* costH = costTH + 2 * BND;        // 2*BND fp16: cost (row-major)
  const long needElems = (long)(costH - (u16*)d_ws) + 2 * BND;
  const bool haveCH = (long)ws_size >= needElems * 2;

  const dim3 blk(256), blk5(512);
  // one-time prep
  tcvt<0><<<dim3(4, 4, 10), blk, 0, stream>>>(Wq, WqT, 256, 256, nullptr, 0, nullptr);
  tcvt<0><<<dim3(4, 4, 10), blk, 0, stream>>>(Wk, WkT, 256, 256, nullptr, 0, nullptr);
  tcvt<0><<<dim3(4, 4, 10), blk, 0, stream>>>(Wv, WvT, 256, 256, nullptr, 0, nullptr);
  tcvt<0><<<dim3(8, 4, 10), blk, 0, stream>>>(W1, W1T, 256, 512, nullptr, 0, nullptr);
  tcvt<0><<<dim3(4, 8, 10), blk, 0, stream>>>(W2, W2T, 512, 256, nullptr, 0, nullptr);
  cvtb<0><<<1024, blk, 0, stream>>>(in_row, bSt + 0 * BND, BND / 8);
  cvtb<0><<<1024, blk, 0, stream>>>(in_col, bSt + 1 * BND, BND / 8);
  if (haveCH) {
    tcvt<2><<<dim3(8, 8, 128), blk, 0, stream>>>(cost, costTH, 512, 512,
                                                 nullptr, 0, nullptr);
    cvtb<2><<<2048, blk, 0, stream>>>(cost, costH, 2 * BND / 8);
  }

  for (int l = 0; l < kL; ++l) {
    const int inPar = l & 1, outPar = 1 - inPar;
    const u16* bR = bSt + (inPar * 2 + 0) * BND;
    const u16* bC = bSt + (inPar * 2 + 1) * BND;

    for (int side = 0; side < 2; ++side) {
      const u16* xrB = side ? bC : bR;
      const u16* xcB = side ? bR : bC;
      u16* outB = bSt + (outPar * 2 + side) * BND;
      float* outF = side ? outCol : outRow;
      const int pi = l * 2 + side;

      // E = bf16(exp(-alpha*lsc * cost)), oriented for this side's rows
      if (side == 0) {
        if (haveCH)
          eexpH<<<4096, blk, 0, stream>>>(costH, Ebuf, 2 * BND / 8, alpha, pi,
                                          lsc);
        else
          eexp<<<4096, blk, 0, stream>>>(cost, Ebuf, 2 * BND / 8, alpha, pi,
                                         lsc);
      } else if (haveCH) {
        eexpH<<<4096, blk, 0, stream>>>(costTH, Ebuf, 2 * BND / 8, alpha, pi,
                                        lsc);
      } else {
        tcvt<1><<<dim3(8, 8, 128), blk, 0, stream>>>(cost, Ebuf, 512, 512,
                                                     alpha, pi, lsc);
      }

      gemm_mf<EP_SIG, 256><<<1024, blk, 0, stream>>>(
          xrB, WqT + (long)pi * 256 * 256, 2, qb, nullptr, nullptr, nullptr);
      kv_mf<<<1024, blk, 0, stream>>>(xcB, WkT + (long)pi * 256 * 256,
                                      WvT + (long)pi * 256 * 256, CbufT);
      aft_mf<<<1024, blk5, 0, stream>>>(Ebuf, CbufT, qb, xrB, h0b, statsF);
      inormS<false><<<dim3(128, 4, 2), blk, 0, stream>>>(
          h0b, statsF, g1 + pi * 256, be1 + pi * 256, h1b, nullptr);
      gemm_mf<EP_RELUB, 256><<<2048, blk, 0, stream>>>(
          h1b, W1T + (long)pi * 512 * 256, 4, ffmid, b1 + pi * 512, nullptr,
          nullptr);
      gemm_mf<EP_BIASRES, 512><<<1024, blk, 0, stream>>>(
          ffmid, W2T + (long)pi * 256 * 512, 2, h2b, b2 + pi * 256, h1b,
          statsF);
      if (l == kL - 1)
        inormS<true><<<dim3(128, 4, 2), blk, 0, stream>>>(
            h2b, statsF, g2 + pi * 256, be2 + pi * 256, outB, outF);
      else
        inormS<false><<<dim3(128, 4, 2), blk, 0, stream>>>(
            h2b, statsF, g2 + pi * 256, be2 + pi * 256, outB, nullptr);
    }
  }
}

// Round 19
// 3214.572 us; speedup vs baseline: 1.1376x; 1.1376x over previous
//
#include <hip/hip_runtime.h>

typedef unsigned short u16;
typedef __attribute__((ext_vector_type(8))) short short8;
typedef __attribute__((ext_vector_type(4))) float f32x4;

#define DEVFUN __device__ __forceinline__

namespace {

constexpr int kB = 128;
constexpr int kN = 512;   // N == M
constexpr int kD = 256;
constexpr int kF = 512;
constexpr int kL = 5;
constexpr float kEPS = 1e-5f;
constexpr long BND = (long)kB * kN * kD;  // 16,777,216

DEVFUN float bf2f(u16 u) {
  unsigned v = ((unsigned)u) << 16;
  float f;
  __builtin_memcpy(&f, &v, 4);
  return f;
}
DEVFUN u16 f2bf(float f) {  // round-to-nearest-even
  unsigned x;
  __builtin_memcpy(&x, &f, 4);
  x = (x + 0x7FFFu + ((x >> 16) & 1u)) >> 16;
  return (u16)x;
}
DEVFUN u16 f2h(float f) {
  _Float16 h = (_Float16)f;
  u16 u;
  __builtin_memcpy(&u, &h, 2);
  return u;
}
DEVFUN float h2f(u16 u) {
  _Float16 h;
  __builtin_memcpy(&h, &u, 2);
  return (float)h;
}
DEVFUN float fsig(float x) { return 1.f / (1.f + __expf(-x)); }

union Pk8 { u16 p[8]; uint4 v; };
union Pk4 { u16 p[4]; uint2 v; };

// async global->LDS, 16B per lane; LDS dest wave-uniform base + lane*16
DEVFUN void gload16(const u16* g, u16* l) {
  __builtin_amdgcn_global_load_lds(
      (const __attribute__((address_space(1))) void*)g,
      (__attribute__((address_space(3))) void*)l, 16, 0, 0);
}

DEVFUN void waitv8() { asm volatile("s_waitcnt vmcnt(8)" ::: "memory"); }
DEVFUN void waitv0() { asm volatile("s_waitcnt vmcnt(0)" ::: "memory"); }

// ---------------- transpose fp32 -> {bf16, exp-bf16, fp16} ----------------
template <int MODE>
__global__ __launch_bounds__(256) void tcvt(const float* __restrict__ src,
                                            u16* __restrict__ dst, int R,
                                            int C, const float* __restrict__ al,
                                            int pi, const float* __restrict__ ls) {
  __shared__ u16 T[64 * 64];
  const int t = threadIdx.x;
  const long z = blockIdx.z;
  const int cBase = blockIdx.x * 64, rBase = blockIdx.y * 64;
  float s = 0.f;
  if constexpr (MODE == 1) s = -al[pi] * ls[0];
#pragma unroll
  for (int i = 0; i < 4; ++i) {
    int u = i * 256 + t;
    int n = u >> 4, m4 = u & 15;
    float4 v = *(const float4*)(src + (z * R + rBase + n) * C + cBase + m4 * 4);
    Pk4 pk;
    if constexpr (MODE == 1) {
      pk.p[0] = f2bf(__expf(s * v.x)); pk.p[1] = f2bf(__expf(s * v.y));
      pk.p[2] = f2bf(__expf(s * v.z)); pk.p[3] = f2bf(__expf(s * v.w));
    } else if constexpr (MODE == 2) {
      pk.p[0] = f2h(v.x); pk.p[1] = f2h(v.y);
      pk.p[2] = f2h(v.z); pk.p[3] = f2h(v.w);
    } else {
      pk.p[0] = f2bf(v.x); pk.p[1] = f2bf(v.y);
      pk.p[2] = f2bf(v.z); pk.p[3] = f2bf(v.w);
    }
    int ch = (m4 >> 1) ^ ((n >> 3) & 7), hf = m4 & 1;
    *(uint2*)&T[n * 64 + ch * 8 + hf * 4] = pk.v;
  }
  __syncthreads();
#pragma unroll
  for (int j = 0; j < 2; ++j) {
    int u = j * 256 + t;
    int om = u >> 3, nc = u & 7;
    Pk8 pk;
#pragma unroll
    for (int i = 0; i < 8; ++i) {
      int n = nc * 8 + i;
      int ch = (om >> 3) ^ ((n >> 3) & 7);
      pk.p[i] = T[n * 64 + ch * 8 + (om & 7)];
    }
    *(uint4*)(dst + (z * C + cBase + om) * R + rBase + nc * 8) = pk.v;
  }
}

// ------------- elementwise exp from f32: E = bf16(exp(s*x)) --------------
__global__ __launch_bounds__(256) void eexp(const float* __restrict__ src,
                                            u16* __restrict__ dst, long n8,
                                            const float* __restrict__ al,
                                            int pi, const float* __restrict__ ls) {
  const float s = -al[pi] * ls[0];
  for (long i = blockIdx.x * 256 + threadIdx.x; i < n8;
       i += (long)gridDim.x * 256) {
    const float* p = src + i * 8;
    float4 v0 = *(const float4*)p, v1 = *(const float4*)(p + 4);
    Pk8 pk;
    pk.p[0] = f2bf(__expf(s * v0.x)); pk.p[1] = f2bf(__expf(s * v0.y));
    pk.p[2] = f2bf(__expf(s * v0.z)); pk.p[3] = f2bf(__expf(s * v0.w));
    pk.p[4] = f2bf(__expf(s * v1.x)); pk.p[5] = f2bf(__expf(s * v1.y));
    pk.p[6] = f2bf(__expf(s * v1.z)); pk.p[7] = f2bf(__expf(s * v1.w));
    *(uint4*)(dst + i * 8) = pk.v;
  }
}

// ------------- elementwise exp from fp16: E = bf16(exp(s*x)) -------------
__global__ __launch_bounds__(256) void eexpH(const u16* __restrict__ src,
                                             u16* __restrict__ dst, long n8,
                                             const float* __restrict__ al,
                                             int pi, const float* __restrict__ ls) {
  const float s = -al[pi] * ls[0];
  for (long i = blockIdx.x * 256 + threadIdx.x; i < n8;
       i += (long)gridDim.x * 256) {
    Pk8 h;
    h.v = *(const uint4*)(src + i * 8);
    Pk8 pk;
#pragma unroll
    for (int q = 0; q < 8; ++q) pk.p[q] = f2bf(__expf(s * h2f(h.p[q])));
    *(uint4*)(dst + i * 8) = pk.v;
  }
}

// ------------- elementwise fp32 -> bf16 / fp16 ---------------------------
template <int MODE>  // 0 = bf16, 2 = fp16
__global__ __launch_bounds__(256) void cvtb(const float* __restrict__ src,
                                            u16* __restrict__ dst, long n8) {
  for (long i = blockIdx.x * 256 + threadIdx.x; i < n8;
       i += (long)gridDim.x * 256) {
    const float* p = src + i * 8;
    float4 v0 = *(const float4*)p, v1 = *(const float4*)(p + 4);
    Pk8 pk;
    if constexpr (MODE == 2) {
      pk.p[0] = f2h(v0.x); pk.p[1] = f2h(v0.y);
      pk.p[2] = f2h(v0.z); pk.p[3] = f2h(v0.w);
      pk.p[4] = f2h(v1.x); pk.p[5] = f2h(v1.y);
      pk.p[6] = f2h(v1.z); pk.p[7] = f2h(v1.w);
    } else {
      pk.p[0] = f2bf(v0.x); pk.p[1] = f2bf(v0.y);
      pk.p[2] = f2bf(v0.z); pk.p[3] = f2bf(v0.w);
      pk.p[4] = f2bf(v1.x); pk.p[5] = f2bf(v1.y);
      pk.p[6] = f2bf(v1.z); pk.p[7] = f2bf(v1.w);
    }
    *(uint4*)(dst + i * 8) = pk.v;
  }
}

// --------------- shared MFMA inner step (BK=64, 128x128 tile) -------------
DEVFUN void mfma_step(const u16* As, const u16* Bs, int wr, int wc, int lr,
                      int lhi, f32x4 acc[4][4]) {
#pragma unroll
  for (int ks = 0; ks < 2; ++ks) {
    short8 af[4], bfr[4];
#pragma unroll
    for (int m = 0; m < 4; ++m) {
      int r = wr + m * 16 + lr;
      af[m] = *(const short8*)&As[r * 64 + (((ks << 2) + lhi) ^ (r & 7)) * 8];
    }
#pragma unroll
    for (int n = 0; n < 4; ++n) {
      int r = wc + n * 16 + lr;
      bfr[n] = *(const short8*)&Bs[r * 64 + (((ks << 2) + lhi) ^ (r & 7)) * 8];
    }
#pragma unroll
    for (int m = 0; m < 4; ++m)
#pragma unroll
      for (int n = 0; n < 4; ++n)
        acc[m][n] = __builtin_amdgcn_mfma_f32_16x16x32_bf16(af[m], bfr[n],
                                                            acc[m][n], 0, 0, 0);
  }
}

enum Epi { EP_SIG = 0, EP_RELUB, EP_BIASRES };

// C[65536 x NC] = A[65536 x K](bf16) @ WT[NC x K]^T(bf16); 128x128 tile,
// 2-buffer pipeline with counted vmcnt (R12-proven best for weight GEMMs).
// EP_BIASRES additionally emits partial (sum, sumsq) for the next inorm.
template <int EPI, int KK>
__global__ __launch_bounds__(256) void gemm_mf(
    const u16* __restrict__ Asrc, const u16* __restrict__ WT, int gx,
    void* __restrict__ outp, const void* __restrict__ aux,
    const u16* __restrict__ aux2b, float* __restrict__ statsF) {
  __shared__ u16 SM[4 * 8192];  // A0 B0 A1 B1, 16KB each
  const int t = threadIdx.x;
  const int lane = t & 63, wid = t >> 6;
  const int lr = lane & 15, lhi = lane >> 4;
  const int wr = (wid >> 1) * 64, wc = (wid & 1) * 64;
  const int cpx = gridDim.x >> 3;
  const int rb = (blockIdx.x & 7) * cpx + (blockIdx.x >> 3);
  const int bx = rb % gx;
  const long rowBase = (long)(rb / gx) * 128;
  const int colBase = bx * 128;
  const int r0 = wid * 32;
  const int rl = lane >> 3, sl = lane & 7;

  f32x4 acc[4][4];
#pragma unroll
  for (int m = 0; m < 4; ++m)
#pragma unroll
    for (int n = 0; n < 4; ++n) acc[m][n] = {0.f, 0.f, 0.f, 0.f};

  auto stage = [&](int tt, int pb) {
    const int kt = tt << 6;
    u16* As = SM + pb * 16384;
    u16* Bs = SM + pb * 16384 + 8192;
#pragma unroll
    for (int j = 0; j < 4; ++j) {
      int r = r0 + j * 8 + rl;
      int gch = sl ^ (r & 7);
      gload16(Asrc + (rowBase + r) * KK + kt + gch * 8, &As[(r0 + j * 8) * 64]);
      gload16(WT + (long)(colBase + r) * KK + kt + gch * 8,
              &Bs[(r0 + j * 8) * 64]);
    }
  };

  constexpr int NT = KK >> 6;  // 4 or 8
  stage(0, 0);
  stage(1, 1);
  waitv8();
  __builtin_amdgcn_s_barrier();
#pragma unroll
  for (int tt = 0; tt < NT - 1; ++tt) {
    mfma_step(SM + (tt & 1) * 16384, SM + (tt & 1) * 16384 + 8192, wr, wc, lr,
              lhi, acc);
    __builtin_amdgcn_s_barrier();
    if (tt + 2 < NT) {
      stage(tt + 2, tt & 1);
      waitv8();
    } else {
      waitv0();
    }
    __builtin_amdgcn_s_barrier();
  }
  mfma_step(SM + ((NT - 1) & 1) * 16384, SM + ((NT - 1) & 1) * 16384 + 8192,
            wr, wc, lr, lhi, acc);

  float psum[4] = {0.f, 0.f, 0.f, 0.f}, psq[4] = {0.f, 0.f, 0.f, 0.f};
#pragma unroll
  for (int m = 0; m < 4; ++m) {
#pragma unroll
    for (int n = 0; n < 4; ++n) {
#pragma unroll
      for (int rr = 0; rr < 4; ++rr) {
        float v = acc[m][n][rr];
        long grow = rowBase + wr + m * 16 + lhi * 4 + rr;
        int gcol = colBase + wc + n * 16 + lr;
        if constexpr (EPI == EP_SIG) {
          ((u16*)outp)[grow * 256 + gcol] = f2bf(fsig(v));
        } else if constexpr (EPI == EP_RELUB) {
          float bb = ((const float*)aux)[gcol];
          ((u16*)outp)[grow * 512 + gcol] = f2bf(fmaxf(v + bb, 0.f));
        } else {  // EP_BIASRES: bias + bf16 residual -> bf16 state + stats
          float bb = ((const float*)aux)[gcol];
          float y = v + bb + bf2f(aux2b[grow * 256 + gcol]);
          ((u16*)outp)[grow * 256 + gcol] = f2bf(y);
          psum[n] += y;
          psq[n] += y * y;
        }
      }
    }
  }

  if constexpr (EPI == EP_BIASRES) {
    __syncthreads();  // all LDS reads of the K-loop done; SM reuse safe
    float* stS = (float*)SM;        // [8][128]
    float* stQ = stS + 8 * 128;     // [8][128]
    const int ctr = (wid >> 1) * 4 + lhi;
#pragma unroll
    for (int n = 0; n < 4; ++n) {
      stS[ctr * 128 + wc + n * 16 + lr] = psum[n];
      stQ[ctr * 128 + wc + n * 16 + lr] = psq[n];
    }
    __syncthreads();
    if (t < 128) {
      float s = 0.f, q = 0.f;
#pragma unroll
      for (int i = 0; i < 8; ++i) {
        s += stS[i * 128 + t];
        q += stQ[i * 128 + t];
      }
      const long b = rowBase >> 9;
      const int rblk = (int)((rowBase >> 7) & 3);
      const long o = ((b * 4 + rblk) * 256 + colBase + t) * 2;
      statsF[o] = s;
      statsF[o + 1] = q;
    }
  }
}

// ---- fused K/V GEMM (128x128): ek = exp(x@Wk), ekv = ek*(x@Wv), written
// transposed+coalesced into CbufT ([b][d][m] ekv ; [b][256+d][m] ek).
union KvSm {
  struct { u16 A[128 * 64]; u16 Bk[128 * 64]; u16 Bv[128 * 64]; } s;  // 48KB
  u16 T[128 * 128];  // 32KB transpose staging
};

__global__ __launch_bounds__(256) void kv_mf(const u16* __restrict__ Asrc,
                                             const u16* __restrict__ WkT,
                                             const u16* __restrict__ WvT,
                                             u16* __restrict__ Cb) {
  __shared__ KvSm sm;
  const int t = threadIdx.x;
  const int lane = t & 63, wid = t >> 6;
  const int lr = lane & 15, lhi = lane >> 4;
  const int wr = (wid >> 1) * 64, wc = (wid & 1) * 64;
  const int cpx = gridDim.x >> 3;
  const int rb = (blockIdx.x & 7) * cpx + (blockIdx.x >> 3);
  const long rowBase = (long)(rb >> 1) * 128;
  const int colBase = (rb & 1) * 128;
  const long b = rowBase >> 9;
  const int mInB = (int)(rowBase & 511);
  const int r0 = wid * 32;
  const int rl = lane >> 3, sl = lane & 7;

  f32x4 ka[4][4], va[4][4];
#pragma unroll
  for (int m = 0; m < 4; ++m)
#pragma unroll
    for (int n = 0; n < 4; ++n) {
      ka[m][n] = {0.f, 0.f, 0.f, 0.f};
      va[m][n] = {0.f, 0.f, 0.f, 0.f};
    }

  for (int kt = 0; kt < 256; kt += 64) {
#pragma unroll
    for (int j = 0; j < 4; ++j) {
      int r = r0 + j * 8 + rl;
      int gch = sl ^ (r & 7);
      gload16(Asrc + (rowBase + r) * 256 + kt + gch * 8,
              &sm.s.A[(r0 + j * 8) * 64]);
      gload16(WkT + (long)(colBase + r) * 256 + kt + gch * 8,
              &sm.s.Bk[(r0 + j * 8) * 64]);
      gload16(WvT + (long)(colBase + r) * 256 + kt + gch * 8,
              &sm.s.Bv[(r0 + j * 8) * 64]);
    }
    __syncthreads();
    mfma_step(sm.s.A, sm.s.Bk, wr, wc, lr, lhi, ka);
    mfma_step(sm.s.A, sm.s.Bv, wr, wc, lr, lhi, va);
    __syncthreads();
  }

#pragma unroll
  for (int pass = 0; pass < 2; ++pass) {
#pragma unroll
    for (int m = 0; m < 4; ++m) {
#pragma unroll
      for (int n = 0; n < 4; ++n) {
        int m0 = wr + m * 16 + lhi * 4;
        int d = wc + n * 16 + lr;
        Pk4 pk;
#pragma unroll
        for (int rr = 0; rr < 4; ++rr) {
          float ek = __expf(ka[m][n][rr]);
          pk.p[rr] = f2bf(pass ? ek * va[m][n][rr] : ek);
        }
        int slot = (m0 >> 3) ^ (d & 7);
        *(uint2*)&sm.T[d * 128 + slot * 8 + (m0 & 7)] = pk.v;
      }
    }
    __syncthreads();
    const long rbase = b * 512 + (pass ? 0 : 256) + colBase;
#pragma unroll
    for (int j = 0; j < 8; ++j) {
      int idx = j * 256 + t;
      int d = idx >> 4, c = idx & 15;
      uint4 v = *(const uint4*)&sm.T[d * 128 + ((c ^ (d & 7)) * 8)];
      *(uint4*)(Cb + (rbase + d) * 512 + mInB + c * 8) = v;
    }
    __syncthreads();
  }
}

// ---- fused AFT: num & den in one 128x128 block; bf16 output + stats. ----
union SmU {
  struct { u16 A[128 * 64]; u16 B[128 * 64]; } s;
  struct { float den[128 * 68]; float st[2][8][64]; } d;  // 38.9KB total
};

__global__ __launch_bounds__(256) void aft_mf(
    const u16* __restrict__ Ebuf, const u16* __restrict__ CbufT,
    const u16* __restrict__ qb, const u16* __restrict__ xrB,
    u16* __restrict__ dst, float* __restrict__ statsF) {
  __shared__ SmU sm;
  const int t = threadIdx.x;
  const int lane = t & 63, wid = t >> 6;
  const int lr = lane & 15, lhi = lane >> 4;
  const int wr = (wid >> 1) * 64, wc = (wid & 1) * 64;
  const int rb = (blockIdx.x & 7) * 256 + (blockIdx.x >> 3);
  const long b = rb >> 4;
  const int nBase = ((rb >> 2) & 3) * 128;
  const int dBase = (rb & 3) * 64;
  const int r0 = wid * 32;
  const int rl = lane >> 3, sl = lane & 7;

  f32x4 acc[4][4];
#pragma unroll
  for (int m = 0; m < 4; ++m)
#pragma unroll
    for (int n = 0; n < 4; ++n) acc[m][n] = {0.f, 0.f, 0.f, 0.f};

  for (int kt = 0; kt < 512; kt += 64) {
#pragma unroll
    for (int j = 0; j < 4; ++j) {
      int r = r0 + j * 8 + rl;
      int gch = sl ^ (r & 7);
      gload16(Ebuf + (b * 512 + nBase + r) * 512 + kt + gch * 8,
              &sm.s.A[(r0 + j * 8) * 64]);
      int gslot = (r < 64) ? (dBase + r) : (256 + dBase + (r - 64));
      gload16(CbufT + (b * 512 + gslot) * 512 + kt + gch * 8,
              &sm.s.B[(r0 + j * 8) * 64]);
    }
    __syncthreads();
    mfma_step(sm.s.A, sm.s.B, wr, wc, lr, lhi, acc);
    __syncthreads();
  }

  if (wc == 64) {  // den waves -> LDS
#pragma unroll
    for (int m = 0; m < 4; ++m)
#pragma unroll
      for (int n = 0; n < 4; ++n)
#pragma unroll
        for (int rr = 0; rr < 4; ++rr) {
          int nl = wr + m * 16 + lhi * 4 + rr;
          int dl = n * 16 + lr;
          sm.d.den[nl * 68 + dl] = acc[m][n][rr];
        }
  }
  __syncthreads();
  float psum[4] = {0.f, 0.f, 0.f, 0.f}, psq[4] = {0.f, 0.f, 0.f, 0.f};
  if (wc == 0) {  // num waves: combine + epilogue + partial stats
#pragma unroll
    for (int m = 0; m < 4; ++m)
#pragma unroll
      for (int n = 0; n < 4; ++n)
#pragma unroll
        for (int rr = 0; rr < 4; ++rr) {
          int nl = wr + m * 16 + lhi * 4 + rr;
          int dl = n * 16 + lr;
          float dv = sm.d.den[nl * 68 + dl];
          float w = acc[m][n][rr] / dv;
          if (!(w == w)) w = 0.f;
          else if (w > 3.402823466e38f) w = 3.402823466e38f;
          else if (w < -3.402823466e38f) w = -3.402823466e38f;
          long grow = b * 512 + nBase + nl;
          int gcol = dBase + dl;
          float sq = bf2f(qb[grow * 256 + gcol]);
          float y = bf2f(xrB[grow * 256 + gcol]) + sq * w;
          dst[grow * 256 + gcol] = f2bf(y);
          psum[n] += y;
          psq[n] += y * y;
        }
  }
  __syncthreads();  // den reads complete; st region write safe
  if (wc == 0) {
    const int ctr = (wid >> 1) * 4 + lhi;
#pragma unroll
    for (int n = 0; n < 4; ++n) {
      sm.d.st[0][ctr][n * 16 + lr] = psum[n];
      sm.d.st[1][ctr][n * 16 + lr] = psq[n];
    }
  }
  __syncthreads();
  if (t < 64) {
    float s = 0.f, q = 0.f;
#pragma unroll
    for (int i = 0; i < 8; ++i) {
      s += sm.d.st[0][i][t];
      q += sm.d.st[1][i][t];
    }
    const long o = ((b * 4 + (nBase >> 7)) * 256 + dBase + t) * 2;
    statsF[o] = s;
    statsF[o + 1] = q;
  }
}

// ----- instance norm apply (single pass); stats from producer kernels -----
// Scalar access pattern (measured faster than vectorized); rows split
// across blockIdx.z for extra TLP.
template <bool LASTF32>
__global__ __launch_bounds__(256) void inormS(const u16* __restrict__ Xin,
                                              const float* __restrict__ stats,
                                              const float* __restrict__ g,
                                              const float* __restrict__ be,
                                              u16* __restrict__ Xb,
                                              float* __restrict__ Xf) {
  const int b = blockIdx.x;
  const int ch0 = blockIdx.y * 64;
  const int nlo = blockIdx.z * 256;
  const int t = threadIdx.x;
  const int lc = t & 63;
  const int ch = ch0 + lc;
  const int nr = t >> 6;
  const long base = (long)b * kN * kD + ch;

  __shared__ float s1[4][64], s2[4][64];
  __shared__ float mu[64], rs[64], gg[64], bb[64];
  {
    const long o = (((long)b * 4 + nr) * 256 + ch) * 2;
    s1[nr][lc] = stats[o];
    s2[nr][lc] = stats[o + 1];
  }
  __syncthreads();
  if (t < 64) {
    float ssum = s1[0][t] + s1[1][t] + s1[2][t] + s1[3][t];
    float ssq = s2[0][t] + s2[1][t] + s2[2][t] + s2[3][t];
    float m = ssum * (1.f / kN);
    float v = ssq * (1.f / kN) - m * m;
    mu[t] = m;
    rs[t] = rsqrtf(v + kEPS);
    gg[t] = g[ch0 + t];
    bb[t] = be[ch0 + t];
  }
  __syncthreads();
  const float m = mu[lc], rr = rs[lc], G = gg[lc], Bt = bb[lc];
  for (int n = nlo + nr; n < nlo + 256; n += 4) {
    long idx = base + (long)n * kD;
    float y = (bf2f(Xin[idx]) - m) * rr * G + Bt;
    Xb[idx] = f2bf(y);
    if constexpr (LASTF32) Xf[idx] = y;
  }
}

}  // namespace

extern "C" void kernel_launch(void* const* d_in, const int* in_sizes, int n_in,
                              void* d_out, int out_size, void* d_ws,
                              size_t ws_size, hipStream_t stream) {
  (void)in_sizes; (void)n_in; (void)out_size;

  const float* in_row = (const float*)d_in[0];
  const float* in_col = (const float*)d_in[1];
  const float* cost = (const float*)d_in[2];
  const float* lsc = (const float*)d_in[3];
  const float* Wq = (const float*)d_in[4];
  const float* Wk = (const float*)d_in[5];
  const float* Wv = (const float*)d_in[6];
  const float* g1 = (const float*)d_in[7];
  const float* be1 = (const float*)d_in[8];
  const float* W1 = (const float*)d_in[9];
  const float* b1 = (const float*)d_in[10];
  const float* W2 = (const float*)d_in[11];
  const float* b2 = (const float*)d_in[12];
  const float* g2 = (const float*)d_in[13];
  const float* be2 = (const float*)d_in[14];
  const float* alpha = (const float*)d_in[15];

  float* outRow = (float*)d_out;
  float* outCol = outRow + BND;

  u16* qb = (u16*)d_ws;                 // BND (sigmoid q; alias h1b)
  u16* h1b = qb;
  u16* CbufT = qb + BND;                // 2*BND
  u16* ffmid = CbufT;                   // alias (dead after AFT)
  u16* Ebuf = CbufT + 2 * BND;          // 2*BND
  u16* bSt = Ebuf + 2 * BND;            // 4*BND states [parity][side]
  u16* h0b = bSt + 4 * BND;             // BND (aft out; alias h2b)
  u16* h2b = h0b;
  u16* WqT = h0b + BND;
  u16* WkT = WqT + 10L * 256 * 256;
  u16* WvT = WkT + 10L * 256 * 256;
  u16* W1T = WvT + 10L * 256 * 256;     // [pi][f=512][d=256]
  u16* W2T = W1T + 10L * 512 * 256;     // [pi][d=256][f=512]
  float* statsF = (float*)(W2T + 10L * 256 * 512);  // [128][4][256][2] f32
  u16* costTH = (u16*)(statsF + 128L * 4 * 256 * 2);  // 2*BND fp16: cost^T
  u16* costH = costTH + 2 * BND;        // 2*BND fp16: cost (row-major)
  const long needElems = (long)(costH - (u16*)d_ws) + 2 * BND;
  const bool haveCH = (long)ws_size >= needElems * 2;

  const dim3 blk(256);
  // one-time prep
  tcvt<0><<<dim3(4, 4, 10), blk, 0, stream>>>(Wq, WqT, 256, 256, nullptr, 0, nullptr);
  tcvt<0><<<dim3(4, 4, 10), blk, 0, stream>>>(Wk, WkT, 256, 256, nullptr, 0, nullptr);
  tcvt<0><<<dim3(4, 4, 10), blk, 0, stream>>>(Wv, WvT, 256, 256, nullptr, 0, nullptr);
  tcvt<0><<<dim3(8, 4, 10), blk, 0, stream>>>(W1, W1T, 256, 512, nullptr, 0, nullptr);
  tcvt<0><<<dim3(4, 8, 10), blk, 0, stream>>>(W2, W2T, 512, 256, nullptr, 0, nullptr);
  cvtb<0><<<1024, blk, 0, stream>>>(in_row, bSt + 0 * BND, BND / 8);
  cvtb<0><<<1024, blk, 0, stream>>>(in_col, bSt + 1 * BND, BND / 8);
  if (haveCH) {
    tcvt<2><<<dim3(8, 8, 128), blk, 0, stream>>>(cost, costTH, 512, 512,
                                                 nullptr, 0, nullptr);
    cvtb<2><<<2048, blk, 0, stream>>>(cost, costH, 2 * BND / 8);
  }

  for (int l = 0; l < kL; ++l) {
    const int inPar = l & 1, outPar = 1 - inPar;
    const u16* bR = bSt + (inPar * 2 + 0) * BND;
    const u16* bC = bSt + (inPar * 2 + 1) * BND;

    for (int side = 0; side < 2; ++side) {
      const u16* xrB = side ? bC : bR;
      const u16* xcB = side ? bR : bC;
      u16* outB = bSt + (outPar * 2 + side) * BND;
      float* outF = side ? outCol : outRow;
      const int pi = l * 2 + side;

      // E = bf16(exp(-alpha*lsc * cost)), oriented for this side's rows
      if (side == 0) {
        if (haveCH)
          eexpH<<<4096, blk, 0, stream>>>(costH, Ebuf, 2 * BND / 8, alpha, pi,
                                          lsc);
        else
          eexp<<<4096, blk, 0, stream>>>(cost, Ebuf, 2 * BND / 8, alpha, pi,
                                         lsc);
      } else if (haveCH) {
        eexpH<<<4096, blk, 0, stream>>>(costTH, Ebuf, 2 * BND / 8, alpha, pi,
                                        lsc);
      } else {
        tcvt<1><<<dim3(8, 8, 128), blk, 0, stream>>>(cost, Ebuf, 512, 512,
                                                     alpha, pi, lsc);
      }

      gemm_mf<EP_SIG, 256><<<1024, blk, 0, stream>>>(
          xrB, WqT + (long)pi * 256 * 256, 2, qb, nullptr, nullptr, nullptr);
      kv_mf<<<1024, blk, 0, stream>>>(xcB, WkT + (long)pi * 256 * 256,
                                      WvT + (long)pi * 256 * 256, CbufT);
      aft_mf<<<2048, blk, 0, stream>>>(Ebuf, CbufT, qb, xrB, h0b, statsF);
      inormS<false><<<dim3(128, 4, 2), blk, 0, stream>>>(
          h0b, statsF, g1 + pi * 256, be1 + pi * 256, h1b, nullptr);
      gemm_mf<EP_RELUB, 256><<<2048, blk, 0, stream>>>(
          h1b, W1T + (long)pi * 512 * 256, 4, ffmid, b1 + pi * 512, nullptr,
          nullptr);
      gemm_mf<EP_BIASRES, 512><<<1024, blk, 0, stream>>>(
          ffmid, W2T + (long)pi * 256 * 512, 2, h2b, b2 + pi * 256, h1b,
          statsF);
      if (l == kL - 1)
        inormS<true><<<dim3(128, 4, 2), blk, 0, stream>>>(
            h2b, statsF, g2 + pi * 256, be2 + pi * 256, outB, outF);
      else
        inormS<false><<<dim3(128, 4, 2), blk, 0, stream>>>(
            h2b, statsF, g2 + pi * 256, be2 + pi * 256, outB, nullptr);
    }
  }
}